// Round 5
// baseline (478.406 us; speedup 1.0000x reference)
//
#include <hip/hip_runtime.h>

typedef __bf16 bf16;
typedef __bf16 bf16x8 __attribute__((ext_vector_type(8)));
typedef __bf16 bf16x4 __attribute__((ext_vector_type(4)));
typedef float f32x4 __attribute__((ext_vector_type(4)));

static __device__ __forceinline__ f32x4 mfma16(bf16x8 a, bf16x8 b, f32x4 c) {
  return __builtin_amdgcn_mfma_f32_16x16x32_bf16(a, b, c, 0, 0, 0);
}

// load 8 consecutive f32, convert to bf16x8 fragment
static __device__ __forceinline__ bf16x8 ld_bf8(const float* __restrict__ p) {
  f32x4 a = *(const f32x4*)p;
  f32x4 b = *(const f32x4*)(p + 4);
  bf16x8 r;
  r[0] = (bf16)a[0]; r[1] = (bf16)a[1]; r[2] = (bf16)a[2]; r[3] = (bf16)a[3];
  r[4] = (bf16)b[0]; r[5] = (bf16)b[1]; r[6] = (bf16)b[2]; r[7] = (bf16)b[3];
  return r;
}

// ---------------------------------------------------------------- k0: prep
// blocks 0..63:    weights -> bf16 (wb 384x128, pwb 128x128)
// blocks 64..319:  rpb gather -> rb bf16 (4,256,256)
// blocks 320..1343: mask -> bf16 mb (64,256,256), 4 f32x4 per thread
__global__ void k0_prep(const float* __restrict__ qw, const float* __restrict__ pw,
                        const float* __restrict__ bt, const int* __restrict__ ri,
                        const float* __restrict__ mask, bf16* __restrict__ wb,
                        bf16* __restrict__ pwb, bf16* __restrict__ rb,
                        bf16* __restrict__ mb) {
  const int bid = blockIdx.x;
  if (bid < 64) {  // t in [0,16384): 12288 qkv_w f32x4 + 4096 proj_w f32x4
    const int t = bid * 256 + threadIdx.x;
    if (t < 12288) {
      f32x4 v = *(const f32x4*)(qw + (size_t)t * 4);
      bf16x4 o;
#pragma unroll
      for (int r = 0; r < 4; ++r) o[r] = (bf16)v[r];
      *(bf16x4*)(wb + (size_t)t * 4) = o;
    } else {
      const int u = t - 12288;
      f32x4 v = *(const f32x4*)(pw + (size_t)u * 4);
      bf16x4 o;
#pragma unroll
      for (int r = 0; r < 4; ++r) o[r] = (bf16)v[r];
      *(bf16x4*)(pwb + (size_t)u * 4) = o;
    }
  } else if (bid < 320) {
    const int t2 = (bid - 64) * 256 + threadIdx.x;  // [0, 65536)
    const int idx = ri[t2];
    f32x4 v = *(const f32x4*)(bt + idx * 4);
#pragma unroll
    for (int h = 0; h < 4; ++h) rb[h * 65536 + t2] = (bf16)v[h];
  } else {  // mask: 1024 blocks x 256 threads x 4 f32x4 = 1048576 f32x4
    const int mid = bid - 320;
#pragma unroll
    for (int it = 0; it < 4; ++it) {
      const size_t t = (size_t)mid * 1024 + it * 256 + threadIdx.x;
      f32x4 m4 = *(const f32x4*)(mask + t * 4);
      bf16x4 o;
#pragma unroll
      for (int r = 0; r < 4; ++r) o[r] = (bf16)m4[r];
      *(bf16x4*)(mb + t * 4) = o;
    }
  }
}

// ---------------------------------------------------------------- k_main: fully fused
// grid 512 (one block per batch window b), 512 threads = 8 waves.
// Wave wv owns q-rows [wv*32, wv*32+32) (2 stripes of 16).
// Per head h: Q -> wave-private LDS; K,V -> shared LDS (each wave its 32 rows);
// attention (k2's verified S^T=K.Q^T structure, P in wave-private swizzled LDS,
// k-range split in 2 halves so P tile = 16x128 = 4KB); proj accumulated per-head
// into registers (out = sum_h ao_h . Wp_h^T). Q/K/V/ao never touch HBM.
// launch_bounds(512,1): VGPR cap 256 -> no spills (round-4's (512,2) capped at 128
// and spilled ~90MB write + ~140MB fetch of scratch traffic).
__global__ void __launch_bounds__(512, 1)
k_main(const float* __restrict__ x, const bf16* __restrict__ wb,
       const float* __restrict__ qb, const bf16* __restrict__ pwb,
       const float* __restrict__ pbias, const bf16* __restrict__ mb,
       const bf16* __restrict__ rb, float* __restrict__ out) {
  __shared__ bf16 ksm[256 * 32];   // K[b] rows x 32 dims, xor-swizzled   16KB
  __shared__ bf16 vsm[32 * 256];   // V^T dims x keys, xor-swizzled       16KB
  __shared__ bf16 psm[8 * 2048];   // per-wave 4KB: Q(2KB)/P-half(4KB)/ao(1.25KB) 32KB
  const int tid = threadIdx.x, wv = tid >> 6;
  const int ln = tid & 15, qd = (tid >> 4) & 3;
  const int b = blockIdx.x, w = b & 63;
  bf16* pw_ = psm + wv * 2048;  // wave-private region (elements)

  // X fragments for this wave's 32 rows: lane (ln,qd): X[row nt*16+ln][ks*32+qd*8..]
  bf16x8 xf[2][4];
#pragma unroll
  for (int nt = 0; nt < 2; ++nt)
#pragma unroll
    for (int ks = 0; ks < 4; ++ks)
      xf[nt][ks] = ld_bf8(x + (size_t)(b * 256 + wv * 32 + nt * 16 + ln) * 128 +
                          ks * 32 + qd * 8);

  f32x4 acc_out[2][8];  // [si][ct2]: out rows wv*32+si*16+qd*4+r, col ct2*16+ln
#pragma unroll
  for (int si = 0; si < 2; ++si)
#pragma unroll
    for (int ct2 = 0; ct2 < 8; ++ct2) acc_out[si][ct2] = (f32x4){0.f, 0.f, 0.f, 0.f};

  for (int h = 0; h < 4; ++h) {
    // ---- step A: Q for own 32 rows -> pw_[row][d] (transposed orientation, k1)
    {
      f32x4 aq[2][2];
#pragma unroll
      for (int ct = 0; ct < 2; ++ct)
#pragma unroll
        for (int nt = 0; nt < 2; ++nt) aq[ct][nt] = (f32x4){0.f, 0.f, 0.f, 0.f};
#pragma unroll
      for (int ct = 0; ct < 2; ++ct)
#pragma unroll
        for (int ks = 0; ks < 4; ++ks) {
          bf16x8 wf = *(const bf16x8*)(wb + (size_t)(h * 32 + ct * 16 + ln) * 128 +
                                       ks * 32 + qd * 8);
#pragma unroll
          for (int nt = 0; nt < 2; ++nt) aq[ct][nt] = mfma16(wf, xf[nt][ks], aq[ct][nt]);
        }
#pragma unroll
      for (int ct = 0; ct < 2; ++ct) {
        const int c0 = ct * 16 + qd * 4;  // head-local q-dim
        f32x4 b4 = *(const f32x4*)(qb + h * 32 + c0);
#pragma unroll
        for (int nt = 0; nt < 2; ++nt) {
          bf16x4 o;
#pragma unroll
          for (int r = 0; r < 4; ++r)
            o[r] = (bf16)((aq[ct][nt][r] + b4[r]) * 0.17677669529663689f);
          *(bf16x4*)(pw_ + (nt * 16 + ln) * 32 + c0) = o;
        }
      }
    }
    // qf for both stripes (same-wave ds write->read ordering)
    bf16x8 qf0 = *(const bf16x8*)(pw_ + (0 * 16 + ln) * 32 + qd * 8);
    bf16x8 qf1 = *(const bf16x8*)(pw_ + (1 * 16 + ln) * 32 + qd * 8);

    __syncthreads();  // all waves done reading ksm/vsm of head h-1

    // ---- step B: K rows -> ksm (transposed), V rows -> vsm as V^T (normal)
    {
      f32x4 ak[2][2];
#pragma unroll
      for (int ct = 0; ct < 2; ++ct)
#pragma unroll
        for (int nt = 0; nt < 2; ++nt) ak[ct][nt] = (f32x4){0.f, 0.f, 0.f, 0.f};
#pragma unroll
      for (int ct = 0; ct < 2; ++ct)
#pragma unroll
        for (int ks = 0; ks < 4; ++ks) {
          bf16x8 wf = *(const bf16x8*)(wb + (size_t)(128 + h * 32 + ct * 16 + ln) * 128 +
                                       ks * 32 + qd * 8);
#pragma unroll
          for (int nt = 0; nt < 2; ++nt) ak[ct][nt] = mfma16(wf, xf[nt][ks], ak[ct][nt]);
        }
#pragma unroll
      for (int ct = 0; ct < 2; ++ct) {
        const int c0 = ct * 16 + qd * 4;
        f32x4 b4 = *(const f32x4*)(qb + 128 + h * 32 + c0);
        const int slot = ct * 2 + (qd >> 1), off = (qd & 1) * 4;
#pragma unroll
        for (int nt = 0; nt < 2; ++nt) {
          const int grow = wv * 32 + nt * 16 + ln;  // key row
          bf16x4 o;
#pragma unroll
          for (int r = 0; r < 4; ++r) o[r] = (bf16)(ak[ct][nt][r] + b4[r]);
          *(bf16x4*)(ksm + grow * 32 + ((slot ^ (grow & 3)) * 8) + off) = o;
        }
      }
      f32x4 av[2][2];
#pragma unroll
      for (int nt = 0; nt < 2; ++nt)
#pragma unroll
        for (int ct = 0; ct < 2; ++ct) av[nt][ct] = (f32x4){0.f, 0.f, 0.f, 0.f};
#pragma unroll
      for (int ks = 0; ks < 4; ++ks)
#pragma unroll
        for (int ct = 0; ct < 2; ++ct) {
          bf16x8 wf = *(const bf16x8*)(wb + (size_t)(256 + h * 32 + ct * 16 + ln) * 128 +
                                       ks * 32 + qd * 8);
#pragma unroll
          for (int nt = 0; nt < 2; ++nt) av[nt][ct] = mfma16(xf[nt][ks], wf, av[nt][ct]);
        }
#pragma unroll
      for (int nt = 0; nt < 2; ++nt)
#pragma unroll
        for (int ct = 0; ct < 2; ++ct) {
          const int c = ct * 16 + ln;                     // head-local v-dim
          const float bb = qb[256 + h * 32 + c];
          const int n0 = wv * 32 + nt * 16 + qd * 4;     // key rows n0..n0+3
          const int slot = n0 >> 3, off = (qd & 1) * 4;
          bf16x4 o;
#pragma unroll
          for (int r = 0; r < 4; ++r) o[r] = (bf16)(av[nt][ct][r] + bb);
          *(bf16x4*)(vsm + c * 256 + ((slot ^ (c & 7)) * 8) + off) = o;
        }
    }
    __syncthreads();  // K,V of head h ready

    // ---- step C: attention + proj accumulate, per stripe
#pragma unroll
    for (int si = 0; si < 2; ++si) {
      const bf16x8 qf = si ? qf1 : qf0;
      const int n = wv * 32 + si * 16 + ln;  // this lane's q-row
      float sum = 0.f;
      f32x4 accO[2];
      accO[0] = (f32x4){0.f, 0.f, 0.f, 0.f};
      accO[1] = (f32x4){0.f, 0.f, 0.f, 0.f};
#pragma unroll
      for (int hf = 0; hf < 2; ++hf) {  // k-range halves of 128 keys
        f32x4 acc[8];
#pragma unroll
        for (int mt = 0; mt < 8; ++mt) acc[mt] = (f32x4){0.f, 0.f, 0.f, 0.f};
#pragma unroll
        for (int mt = 0; mt < 8; ++mt) {
          const int m = hf * 128 + mt * 16 + ln;
          bf16x8 af = *(const bf16x8*)(ksm + m * 32 + ((qd ^ (m & 3)) * 8));
          acc[mt] = mfma16(af, qf, acc[mt]);  // lane: key=base+qd*4+r, qrow=ln
        }
#pragma unroll
        for (int mt = 0; mt < 8; ++mt) {  // logits + exp (no max-sub: |logit| < ~8)
          const int mcol = hf * 128 + mt * 16 + qd * 4;
          bf16x4 m4 = *(const bf16x4*)(mb + ((size_t)w * 256 + n) * 256 + mcol);
          bf16x4 r4 = *(const bf16x4*)(rb + (size_t)h * 65536 + n * 256 + mcol);
          bf16x4 pv;
#pragma unroll
          for (int r = 0; r < 4; ++r) {
            float p = __expf(acc[mt][r] + (float)m4[r] + (float)r4[r]);
            sum += p;
            pv[r] = (bf16)p;
          }
          *(bf16x4*)(pw_ + ln * 128 + (((mt * 2 + (qd >> 1)) ^ (ln & 7)) * 8) +
                     (qd & 1) * 4) = pv;
        }
#pragma unroll
        for (int ktl = 0; ktl < 4; ++ktl) {  // partial O = P.V for this half
          const int kt = hf * 4 + ktl;       // global key tile
          bf16x8 pf = *(const bf16x8*)(pw_ + ln * 128 + (((ktl * 4 + qd) ^ (ln & 7)) * 8));
#pragma unroll
          for (int ct = 0; ct < 2; ++ct) {
            const int d = ct * 16 + ln;
            bf16x8 vf = *(const bf16x8*)(vsm + d * 256 + (((kt * 4 + qd) ^ (d & 7)) * 8));
            accO[ct] = mfma16(pf, vf, accO[ct]);
          }
        }
      }
      sum += __shfl_xor(sum, 16);
      sum += __shfl_xor(sum, 32);
      const float linv = 1.0f / sum;
      // ao (scaled) -> wave-private LDS [16 rows][32 dims], stride 40 (pad: 2-way free)
#pragma unroll
      for (int r = 0; r < 4; ++r) {
        const float lb = __shfl(linv, qd * 4 + r);  // row's denom lives at lane ln==row
#pragma unroll
        for (int ct = 0; ct < 2; ++ct)
          pw_[(qd * 4 + r) * 40 + ct * 16 + ln] = (bf16)(accO[ct][r] * lb);
      }
      // proj accumulate: out_rows(si) += ao_h . Wp_h^T
      bf16x8 aof = *(const bf16x8*)(pw_ + ln * 40 + qd * 8);
#pragma unroll
      for (int ct2 = 0; ct2 < 8; ++ct2) {
        bf16x8 wpf = *(const bf16x8*)(pwb + (size_t)(ct2 * 16 + ln) * 128 + h * 32 +
                                      qd * 8);
        acc_out[si][ct2] = mfma16(aof, wpf, acc_out[si][ct2]);
      }
    }
  }

  // ---- epilogue: bias + f32 store
#pragma unroll
  for (int si = 0; si < 2; ++si)
#pragma unroll
    for (int ct2 = 0; ct2 < 8; ++ct2) {
      const int col = ct2 * 16 + ln;
      const float bb = pbias[col];
#pragma unroll
      for (int r = 0; r < 4; ++r)
        out[(size_t)(b * 256 + wv * 32 + si * 16 + qd * 4 + r) * 128 + col] =
            acc_out[si][ct2][r] + bb;
    }
}

// ----------------------------------------------------------------
extern "C" void kernel_launch(void* const* d_in, const int* in_sizes, int n_in,
                              void* d_out, int out_size, void* d_ws, size_t ws_size,
                              hipStream_t stream) {
  const float* x = (const float*)d_in[0];
  const float* mask = (const float*)d_in[1];
  const float* qkv_w = (const float*)d_in[2];
  const float* qkv_b = (const float*)d_in[3];
  const float* proj_w = (const float*)d_in[4];
  const float* proj_b = (const float*)d_in[5];
  const float* bias_table = (const float*)d_in[6];
  const int* rel_idx = (const int*)d_in[7];

  char* ws = (char*)d_ws;
  bf16* wb = (bf16*)ws;                      // qkv_w bf16 (384,128)   96 KB
  bf16* pwb = (bf16*)(ws + 98304);           // proj_w bf16 (128,128)  32 KB
  bf16* rb = (bf16*)(ws + 131072);           // rpb bf16 (4,256,256)  512 KB
  bf16* mb = (bf16*)(ws + 655360);           // mask bf16 (64,256,256) 8.4 MB

  k0_prep<<<dim3(1344), dim3(256), 0, stream>>>(qkv_w, proj_w, bias_table, rel_idx,
                                                mask, wb, pwb, rb, mb);
  k_main<<<dim3(512), dim3(512), 0, stream>>>(x, wb, qkv_b, pwb, proj_b, mb, rb,
                                              (float*)d_out);
}

// Round 7
// 365.087 us; speedup vs baseline: 1.3104x; 1.3104x over previous
//
#include <hip/hip_runtime.h>

typedef __bf16 bf16;
typedef __bf16 bf16x8 __attribute__((ext_vector_type(8)));
typedef __bf16 bf16x4 __attribute__((ext_vector_type(4)));
typedef float f32x4 __attribute__((ext_vector_type(4)));

static __device__ __forceinline__ f32x4 mfma16(bf16x8 a, bf16x8 b, f32x4 c) {
  return __builtin_amdgcn_mfma_f32_16x16x32_bf16(a, b, c, 0, 0, 0);
}

// load 8 consecutive f32, convert to bf16x8 fragment
static __device__ __forceinline__ bf16x8 ld_bf8(const float* __restrict__ p) {
  f32x4 a = *(const f32x4*)p;
  f32x4 b = *(const f32x4*)(p + 4);
  bf16x8 r;
  r[0] = (bf16)a[0]; r[1] = (bf16)a[1]; r[2] = (bf16)a[2]; r[3] = (bf16)a[3];
  r[4] = (bf16)b[0]; r[5] = (bf16)b[1]; r[6] = (bf16)b[2]; r[7] = (bf16)b[3];
  return r;
}

// ---------------------------------------------------------------- k0: prep
// blocks 0..63:    weights -> bf16 (wb 384x128, pwb 128x128)
// blocks 64..319:  rpb gather -> rb bf16 (4,256,256)
// blocks 320..1343: mask -> bf16 mb (64,256,256)
__global__ void k0_prep(const float* __restrict__ qw, const float* __restrict__ pw,
                        const float* __restrict__ bt, const int* __restrict__ ri,
                        const float* __restrict__ mask, bf16* __restrict__ wb,
                        bf16* __restrict__ pwb, bf16* __restrict__ rb,
                        bf16* __restrict__ mb) {
  const int bid = blockIdx.x;
  if (bid < 64) {
    const int t = bid * 256 + threadIdx.x;
    if (t < 12288) {
      f32x4 v = *(const f32x4*)(qw + (size_t)t * 4);
      bf16x4 o;
#pragma unroll
      for (int r = 0; r < 4; ++r) o[r] = (bf16)v[r];
      *(bf16x4*)(wb + (size_t)t * 4) = o;
    } else {
      const int u = t - 12288;
      f32x4 v = *(const f32x4*)(pw + (size_t)u * 4);
      bf16x4 o;
#pragma unroll
      for (int r = 0; r < 4; ++r) o[r] = (bf16)v[r];
      *(bf16x4*)(pwb + (size_t)u * 4) = o;
    }
  } else if (bid < 320) {
    const int t2 = (bid - 64) * 256 + threadIdx.x;  // [0, 65536)
    const int idx = ri[t2];
    f32x4 v = *(const f32x4*)(bt + idx * 4);
#pragma unroll
    for (int h = 0; h < 4; ++h) rb[h * 65536 + t2] = (bf16)v[h];
  } else {  // mask: 1024 blocks x 256 threads x 4 f32x4
    const int mid = bid - 320;
#pragma unroll
    for (int it = 0; it < 4; ++it) {
      const size_t t = (size_t)mid * 1024 + it * 256 + threadIdx.x;
      f32x4 m4 = *(const f32x4*)(mask + t * 4);
      bf16x4 o;
#pragma unroll
      for (int r = 0; r < 4; ++r) o[r] = (bf16)m4[r];
      *(bf16x4*)(mb + t * 4) = o;
    }
  }
}

// ---------------------------------------------------------------- k_main: fused, row-half
// grid 1024: bid = (b>>3)*16 + hb*8 + (b&7)  (both halves of b on same XCD, adjacent)
// 512 threads = 8 waves. Wave wv owns q-rows [hb*128 + wv*16, +16) (ONE stripe).
// X staged once in LDS (bf16, swizzled). Per head: Q (own stripe) -> wave LDS;
// K,V for ALL 256 rows (wave wv computes rows wv*32..+32) -> shared LDS;
// attention in k-quarters (P tile 16x64 in wave LDS); proj accumulated in regs.
// Live regs ~110 < 128 -> no spills (r4/r5 spilled: 2-stripe layout needed ~150).
__global__ void __launch_bounds__(512, 2)
k_main(const float* __restrict__ x, const bf16* __restrict__ wb,
       const float* __restrict__ qb, const bf16* __restrict__ pwb,
       const float* __restrict__ pbias, const bf16* __restrict__ mb,
       const bf16* __restrict__ rb, float* __restrict__ out) {
  __shared__ bf16 xsm[256 * 128];  // X bf16, 16B-block swizzled           64KB
  __shared__ bf16 ksm[256 * 32];   // K rows x 32 dims, xor-swizzled       16KB
  __shared__ bf16 vsm[32 * 256];   // V^T dims x keys, xor-swizzled        16KB
  __shared__ bf16 psm[8 * 1024];   // per-wave 2KB: Q(1KB)/P-quarter(2KB)/ao  16KB
  const int tid = threadIdx.x, wv = tid >> 6;
  const int ln = tid & 15, qd = (tid >> 4) & 3;
  const int bid = blockIdx.x;
  const int hb = (bid >> 3) & 1;
  const int b = ((bid >> 4) << 3) | (bid & 7);
  const int w = b & 63;
  bf16* pw_ = psm + wv * 1024;  // wave-private region

  // ---- stage X (256x128 f32 -> bf16 LDS, swizzled 16B blocks)
  {
    const int cblk = tid & 15, r0 = tid >> 4;  // 16 col-blocks x 32 row-groups
#pragma unroll
    for (int j = 0; j < 8; ++j) {
      const int row = r0 + j * 32;
      bf16x8 v = ld_bf8(x + (size_t)(b * 256 + row) * 128 + cblk * 8);
      *(bf16x8*)(xsm + row * 128 + ((cblk ^ (row & 7)) * 8)) = v;
    }
  }

  // ---- mask for this wave's stripe (h-invariant), kept in 32 VGPRs
  const int n = hb * 128 + wv * 16 + ln;  // this lane's q-row
  bf16x4 cmb[16];
#pragma unroll
  for (int mt = 0; mt < 16; ++mt)
    cmb[mt] = *(const bf16x4*)(mb + ((size_t)w * 256 + n) * 256 + mt * 16 + qd * 4);

  f32x4 acc_out[8];  // [ct2]: out rows hb*128+wv*16+qd*4+r, col ct2*16+ln
#pragma unroll
  for (int ct2 = 0; ct2 < 8; ++ct2) acc_out[ct2] = (f32x4){0.f, 0.f, 0.f, 0.f};

  __syncthreads();  // xsm ready

#pragma unroll 1
  for (int h = 0; h < 4; ++h) {
    // ---- step A: Q for own 16-row stripe -> pw_[row][d]
    bf16x8 qf;
    {
      bf16x8 xq[4];
#pragma unroll
      for (int ks = 0; ks < 4; ++ks)
        xq[ks] = *(const bf16x8*)(xsm + n * 128 + (((ks * 4 + qd) ^ (ln & 7)) * 8));
      f32x4 aq[2];
      aq[0] = (f32x4){0.f, 0.f, 0.f, 0.f};
      aq[1] = (f32x4){0.f, 0.f, 0.f, 0.f};
#pragma unroll
      for (int ct = 0; ct < 2; ++ct)
#pragma unroll
        for (int ks = 0; ks < 4; ++ks) {
          bf16x8 wf = *(const bf16x8*)(wb + (size_t)(h * 32 + ct * 16 + ln) * 128 +
                                       ks * 32 + qd * 8);
          aq[ct] = mfma16(wf, xq[ks], aq[ct]);
        }
#pragma unroll
      for (int ct = 0; ct < 2; ++ct) {
        const int c0 = ct * 16 + qd * 4;
        f32x4 b4 = *(const f32x4*)(qb + h * 32 + c0);
        bf16x4 o;
#pragma unroll
        for (int r = 0; r < 4; ++r)
          o[r] = (bf16)((aq[ct][r] + b4[r]) * 0.17677669529663689f);
        *(bf16x4*)(pw_ + ln * 32 + c0) = o;
      }
      qf = *(const bf16x8*)(pw_ + ln * 32 + qd * 8);
    }
    __syncthreads();  // all waves done reading ksm/vsm of head h-1

    // ---- step B: K rows -> ksm (transposed), V rows -> vsm as V^T
    {
      bf16x8 xf[2][4];  // this wave's K/V source rows wv*32..+32
#pragma unroll
      for (int nt = 0; nt < 2; ++nt)
#pragma unroll
        for (int ks = 0; ks < 4; ++ks) {
          const int row = wv * 32 + nt * 16 + ln;
          xf[nt][ks] =
              *(const bf16x8*)(xsm + row * 128 + (((ks * 4 + qd) ^ (row & 7)) * 8));
        }
      f32x4 ak[2][2];
#pragma unroll
      for (int ct = 0; ct < 2; ++ct)
#pragma unroll
        for (int nt = 0; nt < 2; ++nt) ak[ct][nt] = (f32x4){0.f, 0.f, 0.f, 0.f};
#pragma unroll
      for (int ct = 0; ct < 2; ++ct)
#pragma unroll
        for (int ks = 0; ks < 4; ++ks) {
          bf16x8 wf = *(const bf16x8*)(wb + (size_t)(128 + h * 32 + ct * 16 + ln) * 128 +
                                       ks * 32 + qd * 8);
#pragma unroll
          for (int nt = 0; nt < 2; ++nt) ak[ct][nt] = mfma16(wf, xf[nt][ks], ak[ct][nt]);
        }
#pragma unroll
      for (int ct = 0; ct < 2; ++ct) {
        const int c0 = ct * 16 + qd * 4;
        f32x4 b4 = *(const f32x4*)(qb + 128 + h * 32 + c0);
        const int slot = ct * 2 + (qd >> 1), off = (qd & 1) * 4;
#pragma unroll
        for (int nt = 0; nt < 2; ++nt) {
          const int grow = wv * 32 + nt * 16 + ln;  // key row
          bf16x4 o;
#pragma unroll
          for (int r = 0; r < 4; ++r) o[r] = (bf16)(ak[ct][nt][r] + b4[r]);
          *(bf16x4*)(ksm + grow * 32 + ((slot ^ (grow & 3)) * 8) + off) = o;
        }
      }
      f32x4 av[2][2];
#pragma unroll
      for (int nt = 0; nt < 2; ++nt)
#pragma unroll
        for (int ct = 0; ct < 2; ++ct) av[nt][ct] = (f32x4){0.f, 0.f, 0.f, 0.f};
#pragma unroll
      for (int ks = 0; ks < 4; ++ks)
#pragma unroll
        for (int ct = 0; ct < 2; ++ct) {
          bf16x8 wf = *(const bf16x8*)(wb + (size_t)(256 + h * 32 + ct * 16 + ln) * 128 +
                                       ks * 32 + qd * 8);
#pragma unroll
          for (int nt = 0; nt < 2; ++nt) av[nt][ct] = mfma16(xf[nt][ks], wf, av[nt][ct]);
        }
#pragma unroll
      for (int nt = 0; nt < 2; ++nt)
#pragma unroll
        for (int ct = 0; ct < 2; ++ct) {
          const int c = ct * 16 + ln;                 // head-local v-dim
          const float bb = qb[256 + h * 32 + c];
          const int n0 = wv * 32 + nt * 16 + qd * 4;  // key rows n0..n0+3
          const int slot = n0 >> 3, off = (qd & 1) * 4;
          bf16x4 o;
#pragma unroll
          for (int r = 0; r < 4; ++r) o[r] = (bf16)(av[nt][ct][r] + bb);
          *(bf16x4*)(vsm + c * 256 + ((slot ^ (c & 7)) * 8) + off) = o;
        }
    }
    __syncthreads();  // K,V of head h ready

    // ---- step C: attention (k-quarters) + proj accumulate
    {
      float sum = 0.f;
      f32x4 accO[2];
      accO[0] = (f32x4){0.f, 0.f, 0.f, 0.f};
      accO[1] = (f32x4){0.f, 0.f, 0.f, 0.f};
#pragma unroll
      for (int hq = 0; hq < 4; ++hq) {  // 4 quarters of 64 keys
        f32x4 acc[4];
#pragma unroll
        for (int mt = 0; mt < 4; ++mt) acc[mt] = (f32x4){0.f, 0.f, 0.f, 0.f};
#pragma unroll
        for (int mt = 0; mt < 4; ++mt) {
          const int m = hq * 64 + mt * 16 + ln;
          bf16x8 af = *(const bf16x8*)(ksm + m * 32 + ((qd ^ (m & 3)) * 8));
          acc[mt] = mfma16(af, qf, acc[mt]);  // lane: key=base+qd*4+r, qrow=ln
        }
#pragma unroll
        for (int mt = 0; mt < 4; ++mt) {  // logits + exp (no max-sub: |logit| < ~8)
          const int mcol = hq * 64 + mt * 16 + qd * 4;
          bf16x4 r4 = *(const bf16x4*)(rb + (size_t)h * 65536 + n * 256 + mcol);
          const bf16x4 cm = cmb[hq * 4 + mt];
          bf16x4 pv;
#pragma unroll
          for (int r = 0; r < 4; ++r) {
            float p = __expf(acc[mt][r] + (float)cm[r] + (float)r4[r]);
            sum += p;
            pv[r] = (bf16)p;
          }
          *(bf16x4*)(pw_ + ln * 64 + (((mt * 2 + (qd >> 1)) ^ (ln & 7)) * 8) +
                     (qd & 1) * 4) = pv;
        }
#pragma unroll
        for (int ktl = 0; ktl < 2; ++ktl) {  // partial O = P.V for this quarter
          const int kt = hq * 2 + ktl;       // global 32-key tile
          bf16x8 pf =
              *(const bf16x8*)(pw_ + ln * 64 + (((ktl * 4 + qd) ^ (ln & 7)) * 8));
#pragma unroll
          for (int ct = 0; ct < 2; ++ct) {
            const int d = ct * 16 + ln;
            bf16x8 vf =
                *(const bf16x8*)(vsm + d * 256 + (((kt * 4 + qd) ^ (d & 7)) * 8));
            accO[ct] = mfma16(pf, vf, accO[ct]);
          }
        }
      }
      sum += __shfl_xor(sum, 16);
      sum += __shfl_xor(sum, 32);
      const float linv = 1.0f / sum;
      // ao (normalized) -> wave LDS [16 rows][32 dims], stride 40 (2-way free)
#pragma unroll
      for (int r = 0; r < 4; ++r) {
        const float lb = __shfl(linv, qd * 4 + r);  // row's denom lives at lane ln==row
#pragma unroll
        for (int ct = 0; ct < 2; ++ct)
          pw_[(qd * 4 + r) * 40 + ct * 16 + ln] = (bf16)(accO[ct][r] * lb);
      }
      // proj accumulate: out_rows += ao_h . Wp_h^T
      bf16x8 aof = *(const bf16x8*)(pw_ + ln * 40 + qd * 8);
#pragma unroll
      for (int ct2 = 0; ct2 < 8; ++ct2) {
        bf16x8 wpf =
            *(const bf16x8*)(pwb + (size_t)(ct2 * 16 + ln) * 128 + h * 32 + qd * 8);
        acc_out[ct2] = mfma16(aof, wpf, acc_out[ct2]);
      }
    }
  }

  // ---- epilogue: bias + f32 store
#pragma unroll
  for (int ct2 = 0; ct2 < 8; ++ct2) {
    const int col = ct2 * 16 + ln;
    const float bb = pbias[col];
#pragma unroll
    for (int r = 0; r < 4; ++r)
      out[(size_t)(b * 256 + hb * 128 + wv * 16 + qd * 4 + r) * 128 + col] =
          acc_out[ct2][r] + bb;
  }
}

// ----------------------------------------------------------------
extern "C" void kernel_launch(void* const* d_in, const int* in_sizes, int n_in,
                              void* d_out, int out_size, void* d_ws, size_t ws_size,
                              hipStream_t stream) {
  const float* x = (const float*)d_in[0];
  const float* mask = (const float*)d_in[1];
  const float* qkv_w = (const float*)d_in[2];
  const float* qkv_b = (const float*)d_in[3];
  const float* proj_w = (const float*)d_in[4];
  const float* proj_b = (const float*)d_in[5];
  const float* bias_table = (const float*)d_in[6];
  const int* rel_idx = (const int*)d_in[7];

  char* ws = (char*)d_ws;
  bf16* wb = (bf16*)ws;                      // qkv_w bf16 (384,128)   96 KB
  bf16* pwb = (bf16*)(ws + 98304);           // proj_w bf16 (128,128)  32 KB
  bf16* rb = (bf16*)(ws + 131072);           // rpb bf16 (4,256,256)  512 KB
  bf16* mb = (bf16*)(ws + 655360);           // mask bf16 (64,256,256) 8.4 MB

  k0_prep<<<dim3(1344), dim3(256), 0, stream>>>(qkv_w, proj_w, bias_table, rel_idx,
                                                mask, wb, pwb, rb, mb);
  k_main<<<dim3(1024), dim3(512), 0, stream>>>(x, wb, qkv_b, pwb, proj_b, mb, rb,
                                               (float*)d_out);
}